// Round 11
// baseline (133.490 us; speedup 1.0000x reference)
//
#include <hip/hip_runtime.h>

#define NN 16384      // H*W, 128x128
#define CINC 64

// ---------------------------------------------------------------------------
// k0: fold weights.
// ---------------------------------------------------------------------------
__global__ void gat_k0(const float* __restrict__ w_restore,
                       const float* __restrict__ b_gat,
                       const float* __restrict__ w_reduce,
                       const float* __restrict__ w_lin,
                       const float* __restrict__ att_src,
                       const float* __restrict__ att_dst,
                       float* __restrict__ rb, float* __restrict__ wredT,
                       float* __restrict__ S, float* __restrict__ D) {
    int t = threadIdx.x;
    if (t < 128) {
        int h = t >> 5, k = t & 31;
        float s = 0.f, d = 0.f;
        for (int c = 0; c < 32; ++c) {
            float wl = w_lin[(h * 32 + c) * 32 + k];
            s += att_src[h * 32 + c] * wl;
            d += att_dst[h * 32 + c] * wl;
        }
        S[t] = s; D[t] = d;
    } else if (t < 192) {
        int o = t - 128;
        float r = 0.f;
        for (int c = 0; c < 32; ++c) r += w_restore[o * 32 + c] * b_gat[c];
        rb[o] = r;
    }
    for (int idx = t; idx < 2048; idx += 256) {
        int k = idx & 31, c = idx >> 5;
        wredT[c * 32 + k] = w_reduce[k * 64 + c];
    }
}

// ---------------------------------------------------------------------------
// k1: reduce conv + attention logits. Strip = 64 nodes, 2048 blocks.
// ---------------------------------------------------------------------------
__global__ __launch_bounds__(256) void gat_k1(
        const float* __restrict__ x, const float* __restrict__ wredT,
        const float* __restrict__ S, const float* __restrict__ D,
        float* __restrict__ red_g, float* __restrict__ as_ws,
        float* __restrict__ ad_ws) {
    __shared__ float xs[4096];         // [c][nd] 64x64
    __shared__ float wredT_lds[2048];  // [c][k]
    __shared__ float red_lds[32][64];  // [k][nd]
    __shared__ float Sl[128];
    __shared__ float Dl[128];

    int tid = threadIdx.x;
    int s = blockIdx.x;
    int b = s >> 8;
    int v0 = (s & 255) << 6;

    for (int idx = tid; idx < 2048; idx += 256) wredT_lds[idx] = wredT[idx];
    if (tid < 128) Sl[tid] = S[tid];
    else if (tid < 256 && tid >= 128) Dl[tid - 128] = D[tid - 128];
    const float* xb = x + (size_t)b * CINC * NN + v0;
    for (int idx = tid; idx < 4096; idx += 256) {
        int c = idx >> 6, nd = idx & 63;
        xs[idx] = xb[(size_t)c * NN + nd];           // coalesced 256B rows
    }
    __syncthreads();

    int nd = tid & 63, wv = tid >> 6;

    // ---- phase A: reduced features, 8 k-channels per thread ----
    {
        float acc[8];
#pragma unroll
        for (int kk = 0; kk < 8; ++kk) acc[kk] = 0.f;
        int k0 = wv * 8;
#pragma unroll 4
        for (int c = 0; c < 64; ++c) {
            float xc = xs[c * 64 + nd];
            const float4* wt =
                reinterpret_cast<const float4*>(&wredT_lds[c * 32 + k0]);
            float4 w0 = wt[0], w1 = wt[1];           // broadcast b128
            acc[0] = fmaf(w0.x, xc, acc[0]);
            acc[1] = fmaf(w0.y, xc, acc[1]);
            acc[2] = fmaf(w0.z, xc, acc[2]);
            acc[3] = fmaf(w0.w, xc, acc[3]);
            acc[4] = fmaf(w1.x, xc, acc[4]);
            acc[5] = fmaf(w1.y, xc, acc[5]);
            acc[6] = fmaf(w1.z, xc, acc[6]);
            acc[7] = fmaf(w1.w, xc, acc[7]);
        }
        float* rg = red_g + (size_t)b * 32 * NN + v0 + nd;
#pragma unroll
        for (int kk = 0; kk < 8; ++kk) {
            red_lds[k0 + kk][nd] = acc[kk];
            rg[(size_t)(k0 + kk) * NN] = acc[kk];    // coalesced 256B
        }
    }
    __syncthreads();

    // ---- phase B: logits, head = wave ----
    {
        float rv[32];
#pragma unroll
        for (int k = 0; k < 32; ++k) rv[k] = red_lds[k][nd];
        int h = wv;
        const float4* s4 = reinterpret_cast<const float4*>(&Sl[h * 32]);
        const float4* d4 = reinterpret_cast<const float4*>(&Dl[h * 32]);
        float pas = 0.f, pad_ = 0.f;
#pragma unroll
        for (int k4 = 0; k4 < 8; ++k4) {
            float4 sv = s4[k4], dv = d4[k4];
            pas  += sv.x * rv[4 * k4]     + sv.y * rv[4 * k4 + 1] +
                    sv.z * rv[4 * k4 + 2] + sv.w * rv[4 * k4 + 3];
            pad_ += dv.x * rv[4 * k4]     + dv.y * rv[4 * k4 + 1] +
                    dv.z * rv[4 * k4 + 2] + dv.w * rv[4 * k4 + 3];
        }
        as_ws[((size_t)b * 4 + h) * NN + v0 + nd] = pas;
        ad_ws[((size_t)b * 4 + h) * NN + v0 + nd] = pad_;
    }
}

// ---------------------------------------------------------------------------
// k2: LDS-staged red halo (rounds 8/10: 160 strided L2 loads/thread x ~12
//     waves = unhidden latency; halo staged once, shared by all 4 heads ->
//     stencil becomes ds_read at 5.8cyc, hidden under VALU) + SGPR-weight
//     fold + c-quarter head-reduce (UNION'd with halo LDS: halo dead after
//     stencil) + restore conv + residual + BN partials.
// ---------------------------------------------------------------------------
__global__ __launch_bounds__(256) void gat_k2(
        const float* __restrict__ x, const float* __restrict__ w_lin,
        const float* __restrict__ w_restore, const float* __restrict__ rb,
        const float* __restrict__ red_g, const float* __restrict__ as_ws,
        const float* __restrict__ ad_ws, float* __restrict__ outp,
        float* __restrict__ part) {
    // union: halo sh[32][3][68] (26112B) overlaps gp[4][8][64] (8192B) +
    // gout[32][64] (8192B). halo is dead before gp/gout first write.
    __shared__ __align__(16) char smem[26112];
    float (*sh)[3][68] = reinterpret_cast<float (*)[3][68]>(smem);
    float (*gp)[8][64] = reinterpret_cast<float (*)[8][64]>(smem);
    float (*gout)[64]  = reinterpret_cast<float (*)[64]>(smem + 8192);
    __shared__ float stat_lds[128];

    int tid = threadIdx.x;
    int s = blockIdx.x;
    int b = s >> 8;
    int v0 = (s & 255) << 6;
    int nd = tid & 63;
    int h = __builtin_amdgcn_readfirstlane(tid >> 6);  // wave-uniform head
    int v = v0 + nd;
    int i = v >> 7, j = v & 127;
    int i0 = v0 >> 7, j0 = v0 & 127;    // strip = half an image row

    // ---- stage red halo: 3 rows x 66 cols x 32 k (clamped at borders) ----
    {
        const float* rg = red_g + (size_t)b * 32 * NN;
        for (int idx = tid; idx < 6336; idx += 256) {   // 96*66
            int row = idx / 66, c = idx - row * 66;
            int k = row / 3, r = row - k * 3;
            int ii = i0 + r - 1; ii = ii < 0 ? 0 : (ii > 127 ? 127 : ii);
            int jj = j0 + c - 1; jj = jj < 0 ? 0 : (jj > 127 ? 127 : jj);
            sh[k][r][c] = rg[(size_t)k * NN + ii * 128 + jj];
        }
    }

    // ---- alpha (regs only), head = wave ----
    float a0, a1, a2, a3, a4;
    {
        int un0 = v;
        int un1 = i > 0   ? v - 128 : v;
        int un2 = i < 127 ? v + 128 : v;
        int un3 = j > 0   ? v - 1   : v;
        int un4 = j < 127 ? v + 1   : v;
        const float* asp = as_ws + ((size_t)b * 4 + h) * NN;
        float adv = ad_ws[((size_t)b * 4 + h) * NN + v];
        float e0 = asp[un0] + adv, e1 = asp[un1] + adv, e2 = asp[un2] + adv,
              e3 = asp[un3] + adv, e4 = asp[un4] + adv;
        e0 = e0 > 0.f ? e0 : 0.2f * e0;
        e1 = e1 > 0.f ? e1 : 0.2f * e1;
        e2 = e2 > 0.f ? e2 : 0.2f * e2;
        e3 = e3 > 0.f ? e3 : 0.2f * e3;
        e4 = e4 > 0.f ? e4 : 0.2f * e4;
        e1 += i > 0   ? 0.f : -1e30f;
        e2 += i < 127 ? 0.f : -1e30f;
        e3 += j > 0   ? 0.f : -1e30f;
        e4 += j < 127 ? 0.f : -1e30f;
        float m = fmaxf(fmaxf(fmaxf(e0, e1), fmaxf(e2, e3)), e4);
        e0 = __expf(e0 - m); e1 = __expf(e1 - m); e2 = __expf(e2 - m);
        e3 = __expf(e3 - m); e4 = __expf(e4 - m);
        float sc = 0.25f / (e0 + e1 + e2 + e3 + e4);   // fold head-mean
        a0 = e0 * sc; a1 = e1 * sc; a2 = e2 * sc; a3 = e3 * sc; a4 = e4 * sc;
    }
    __syncthreads();   // halo staged

    // ---- stencil from LDS halo + fold through SGPR w_lin ----
    float gpart[32];
#pragma unroll
    for (int c = 0; c < 32; ++c) gpart[c] = 0.f;

    const float* wl_h = w_lin + (size_t)h * 32 * 32;   // SGPR base
#pragma unroll 1
    for (int kc = 0; kc < 4; ++kc) {
        float racc8[8];
#pragma unroll
        for (int i8 = 0; i8 < 8; ++i8) {
            int k = kc * 8 + i8;
            racc8[i8] = a0 * sh[k][1][1 + nd] + a1 * sh[k][0][1 + nd] +
                        a2 * sh[k][2][1 + nd] + a3 * sh[k][1][nd] +
                        a4 * sh[k][1][2 + nd];
        }
        const float* wk = wl_h + kc * 8;
#pragma unroll
        for (int c = 0; c < 32; ++c) {
            gpart[c] += wk[c * 32 + 0] * racc8[0] + wk[c * 32 + 1] * racc8[1] +
                        wk[c * 32 + 2] * racc8[2] + wk[c * 32 + 3] * racc8[3] +
                        wk[c * 32 + 4] * racc8[4] + wk[c * 32 + 5] * racc8[5] +
                        wk[c * 32 + 6] * racc8[6] + wk[c * 32 + 7] * racc8[7];
        }
    }
    __syncthreads();   // halo dead; gp/gout may now overwrite it

    // ---- head-reduce in c-quarters, fully unrolled (static gpart idx) ----
#pragma unroll
    for (int q = 0; q < 4; ++q) {
#pragma unroll
        for (int cq = 0; cq < 8; ++cq) gp[h][cq][nd] = gpart[q * 8 + cq];
        __syncthreads();
#pragma unroll
        for (int t2 = 0; t2 < 2; ++t2) {
            int cq = h * 2 + t2;
            gout[q * 8 + cq][nd] = gp[0][cq][nd] + gp[1][cq][nd] +
                                   gp[2][cq][nd] + gp[3][cq][nd];
        }
        __syncthreads();
    }

    // ---- restore conv + residual + BN partials: wave owns 16 out-ch ----
    {
        float gv[32];
#pragma unroll
        for (int c = 0; c < 32; ++c) gv[c] = gout[c][nd];
        const float* xb = x + (size_t)b * CINC * NN + v0 + nd;
        float* ob = outp + (size_t)b * CINC * NN + v0 + nd;
        const float* wr_h = w_restore + (size_t)h * 16 * 32;  // SGPR base
#pragma unroll 2
        for (int o16 = 0; o16 < 16; ++o16) {
            int o = h * 16 + o16;
            const float* wr = wr_h + o16 * 32;
            float acc = rb[o];                        // uniform -> s_load
#pragma unroll
            for (int c = 0; c < 32; ++c)
                acc = fmaf(wr[c], gv[c], acc);
            acc += xb[(size_t)o * NN];               // residual
            ob[(size_t)o * NN] = acc;
            float r1 = acc, r2 = acc * acc;
#pragma unroll
            for (int off = 32; off > 0; off >>= 1) {
                r1 += __shfl_xor(r1, off, 64);
                r2 += __shfl_xor(r2, off, 64);
            }
            if (nd == 0) { stat_lds[o] = r1; stat_lds[64 + o] = r2; }
        }
    }
    __syncthreads();
    if (tid < 128) part[(size_t)s * 128 + tid] = stat_lds[tid];  // coalesced
}

// ---------------------------------------------------------------------------
// k2b: reduce per-block partials (2048 x 128, L2-resident) -> stats[128]
// ---------------------------------------------------------------------------
__global__ __launch_bounds__(256) void gat_k2b(
        const float* __restrict__ part, float* __restrict__ stats) {
    __shared__ float red[4];
    int jj = blockIdx.x;       // 0..127: stat index
    int tid = threadIdx.x;
    float acc = 0.f;
    for (int s = tid; s < 2048; s += 256) acc += part[(size_t)s * 128 + jj];
#pragma unroll
    for (int off = 32; off > 0; off >>= 1) acc += __shfl_xor(acc, off, 64);
    int wv = tid >> 6, lane = tid & 63;
    if (lane == 0) red[wv] = acc;
    __syncthreads();
    if (tid == 0) stats[jj] = red[0] + red[1] + red[2] + red[3];
}

// ---------------------------------------------------------------------------
// k3: BN (batch stats) + ReLU, in place on d_out. float4 per thread.
// ---------------------------------------------------------------------------
__global__ __launch_bounds__(256) void gat_k3(
        float* __restrict__ out, const float* __restrict__ stats,
        const float* __restrict__ gamma, const float* __restrict__ beta) {
    int f = blockIdx.x * 256 + threadIdx.x;
    int e = f * 4;
    int c = (e >> 14) & 63;
    const float cnt_inv = 1.f / 131072.f;   // B*H*W
    float mean = stats[c] * cnt_inv;
    float var = stats[64 + c] * cnt_inv - mean * mean;
    float inv = rsqrtf(var + 1e-5f);
    float sc = gamma[c] * inv;
    float sh = beta[c] - mean * sc;
    float4 vv = reinterpret_cast<float4*>(out)[f];
    vv.x = fmaxf(vv.x * sc + sh, 0.f);
    vv.y = fmaxf(vv.y * sc + sh, 0.f);
    vv.z = fmaxf(vv.z * sc + sh, 0.f);
    vv.w = fmaxf(vv.w * sc + sh, 0.f);
    reinterpret_cast<float4*>(out)[f] = vv;
}

// ---------------------------------------------------------------------------
extern "C" void kernel_launch(void* const* d_in, const int* in_sizes, int n_in,
                              void* d_out, int out_size, void* d_ws, size_t ws_size,
                              hipStream_t stream) {
    const float* x         = (const float*)d_in[0];
    const float* w_reduce  = (const float*)d_in[1];
    const float* w_lin     = (const float*)d_in[2];
    const float* att_src   = (const float*)d_in[3];
    const float* att_dst   = (const float*)d_in[4];
    const float* b_gat     = (const float*)d_in[5];
    const float* w_restore = (const float*)d_in[6];
    const float* bn_gamma  = (const float*)d_in[7];
    const float* bn_beta   = (const float*)d_in[8];
    // src/dst (d_in[9], d_in[10]) unused: the grid structure is known.

    float* ws     = (float*)d_ws;
    float* red_g  = ws;                       // 8*32*16384 = 4,194,304
    float* as_ws  = red_g + 4194304;          // 524,288
    float* ad_ws  = as_ws + 524288;           // 524,288
    float* Sf     = ad_ws + 524288;           // 128
    float* Df     = Sf + 128;                 // 128
    float* rbf    = Df + 128;                 // 64
    float* wredT  = rbf + 64;                 // 2048
    float* stats  = wredT + 2048;             // 128
    float* part   = stats + 128;              // 2048*128 = 262,144

    gat_k0<<<1, 256, 0, stream>>>(w_restore, b_gat, w_reduce, w_lin,
                                  att_src, att_dst, rbf, wredT, Sf, Df);
    gat_k1<<<2048, 256, 0, stream>>>(x, wredT, Sf, Df, red_g, as_ws, ad_ws);
    gat_k2<<<2048, 256, 0, stream>>>(x, w_lin, w_restore, rbf, red_g,
                                     as_ws, ad_ws, (float*)d_out, part);
    gat_k2b<<<128, 256, 0, stream>>>(part, stats);
    gat_k3<<<8192, 256, 0, stream>>>((float*)d_out, stats, bn_gamma, bn_beta);
}

// Round 12
// 102.745 us; speedup vs baseline: 1.2992x; 1.2992x over previous
//
#include <hip/hip_runtime.h>

#define NN 16384      // H*W, 128x128
#define CINC 64

// ---------------------------------------------------------------------------
// k0: fold weights.
// ---------------------------------------------------------------------------
__global__ void gat_k0(const float* __restrict__ w_restore,
                       const float* __restrict__ b_gat,
                       const float* __restrict__ w_reduce,
                       const float* __restrict__ w_lin,
                       const float* __restrict__ att_src,
                       const float* __restrict__ att_dst,
                       float* __restrict__ rb, float* __restrict__ wredT,
                       float* __restrict__ S, float* __restrict__ D) {
    int t = threadIdx.x;
    if (t < 128) {
        int h = t >> 5, k = t & 31;
        float s = 0.f, d = 0.f;
        for (int c = 0; c < 32; ++c) {
            float wl = w_lin[(h * 32 + c) * 32 + k];
            s += att_src[h * 32 + c] * wl;
            d += att_dst[h * 32 + c] * wl;
        }
        S[t] = s; D[t] = d;
    } else if (t < 192) {
        int o = t - 128;
        float r = 0.f;
        for (int c = 0; c < 32; ++c) r += w_restore[o * 32 + c] * b_gat[c];
        rb[o] = r;
    }
    for (int idx = t; idx < 2048; idx += 256) {
        int k = idx & 31, c = idx >> 5;
        wredT[c * 32 + k] = w_reduce[k * 64 + c];
    }
}

// ---------------------------------------------------------------------------
// k1: reduce conv + attention logits. Strip = 64 nodes, 2048 blocks.
// Weights (wredT, S, D) are block-uniform -> read via uniform global
// addresses (s_load / constant cache, SGPR FMA operand) instead of LDS:
// removes 128 ds_read_b128 + 9.25KB LDS per block (r7->r8 k2 lesson).
// ---------------------------------------------------------------------------
__global__ __launch_bounds__(256) void gat_k1(
        const float* __restrict__ x, const float* __restrict__ wredT,
        const float* __restrict__ S, const float* __restrict__ D,
        float* __restrict__ red_g, float* __restrict__ as_ws,
        float* __restrict__ ad_ws) {
    __shared__ float xs[4096];         // [c][nd] 64x64
    __shared__ float red_lds[32][64];  // [k][nd]

    int tid = threadIdx.x;
    int s = blockIdx.x;
    int b = s >> 8;
    int v0 = (s & 255) << 6;

    const float* xb = x + (size_t)b * CINC * NN + v0;
    for (int idx = tid; idx < 4096; idx += 256) {
        int c = idx >> 6, nd = idx & 63;
        xs[idx] = xb[(size_t)c * NN + nd];           // coalesced 256B rows
    }
    __syncthreads();

    int nd = tid & 63;
    int wv = __builtin_amdgcn_readfirstlane(tid >> 6);  // wave-uniform

    // ---- phase A: reduced features, 8 k-channels per wave-group ----
    {
        float a0 = 0.f, a1 = 0.f, a2 = 0.f, a3 = 0.f,
              a4 = 0.f, a5 = 0.f, a6 = 0.f, a7 = 0.f;
        const float* wt = wredT + wv * 8;            // uniform base
#pragma unroll 4
        for (int c = 0; c < 64; ++c) {
            float xc = xs[c * 64 + nd];
            const float* w = wt + c * 32;            // uniform -> s_load
            a0 = fmaf(w[0], xc, a0);
            a1 = fmaf(w[1], xc, a1);
            a2 = fmaf(w[2], xc, a2);
            a3 = fmaf(w[3], xc, a3);
            a4 = fmaf(w[4], xc, a4);
            a5 = fmaf(w[5], xc, a5);
            a6 = fmaf(w[6], xc, a6);
            a7 = fmaf(w[7], xc, a7);
        }
        int k0 = wv * 8;
        float* rg = red_g + (size_t)b * 32 * NN + v0 + nd;
        red_lds[k0 + 0][nd] = a0; rg[(size_t)(k0 + 0) * NN] = a0;
        red_lds[k0 + 1][nd] = a1; rg[(size_t)(k0 + 1) * NN] = a1;
        red_lds[k0 + 2][nd] = a2; rg[(size_t)(k0 + 2) * NN] = a2;
        red_lds[k0 + 3][nd] = a3; rg[(size_t)(k0 + 3) * NN] = a3;
        red_lds[k0 + 4][nd] = a4; rg[(size_t)(k0 + 4) * NN] = a4;
        red_lds[k0 + 5][nd] = a5; rg[(size_t)(k0 + 5) * NN] = a5;
        red_lds[k0 + 6][nd] = a6; rg[(size_t)(k0 + 6) * NN] = a6;
        red_lds[k0 + 7][nd] = a7; rg[(size_t)(k0 + 7) * NN] = a7;
    }
    __syncthreads();

    // ---- phase B: logits, head = wave; S/D via uniform s_load ----
    {
        float rv[32];
#pragma unroll
        for (int k = 0; k < 32; ++k) rv[k] = red_lds[k][nd];
        const float* sp = S + wv * 32;               // uniform base
        const float* dp = D + wv * 32;
        float pas = 0.f, pad_ = 0.f;
#pragma unroll
        for (int k = 0; k < 32; ++k) {
            pas  = fmaf(sp[k], rv[k], pas);
            pad_ = fmaf(dp[k], rv[k], pad_);
        }
        as_ws[((size_t)b * 4 + wv) * NN + v0 + nd] = pas;
        ad_ws[((size_t)b * 4 + wv) * NN + v0 + nd] = pad_;
    }
}

// ---------------------------------------------------------------------------
// k2: round-10 structure (best measured: 62.8us). softmax alphas + stencil
//     in reduced space (coalesced L2 global loads) + SGPR-weight fold +
//     c-quarter head-reduce (fully unrolled, static gpart idx) +
//     restore conv (SGPR weights) + residual + BN partials.
// ---------------------------------------------------------------------------
__global__ __launch_bounds__(256) void gat_k2(
        const float* __restrict__ x, const float* __restrict__ w_lin,
        const float* __restrict__ w_restore, const float* __restrict__ rb,
        const float* __restrict__ red_g, const float* __restrict__ as_ws,
        const float* __restrict__ ad_ws, float* __restrict__ outp,
        float* __restrict__ part) {
    __shared__ float gp[4][8][64];    // per-head partial, c-quarter: 8 KB
    __shared__ float gout[32][64];    // reduced g: 8 KB
    __shared__ float stat_lds[128];

    int tid = threadIdx.x;
    int s = blockIdx.x;
    int b = s >> 8;
    int v0 = (s & 255) << 6;
    int nd = tid & 63;
    int h = __builtin_amdgcn_readfirstlane(tid >> 6);  // wave-uniform head
    int v = v0 + nd;
    int i = v >> 7, j = v & 127;

    int un0 = v;
    int un1 = i > 0   ? v - 128 : v;
    int un2 = i < 127 ? v + 128 : v;
    int un3 = j > 0   ? v - 1   : v;
    int un4 = j < 127 ? v + 1   : v;

    // ---- alpha (regs only), head = wave ----
    float a0, a1, a2, a3, a4;
    {
        const float* asp = as_ws + ((size_t)b * 4 + h) * NN;
        float adv = ad_ws[((size_t)b * 4 + h) * NN + v];
        float e0 = asp[un0] + adv, e1 = asp[un1] + adv, e2 = asp[un2] + adv,
              e3 = asp[un3] + adv, e4 = asp[un4] + adv;
        e0 = e0 > 0.f ? e0 : 0.2f * e0;
        e1 = e1 > 0.f ? e1 : 0.2f * e1;
        e2 = e2 > 0.f ? e2 : 0.2f * e2;
        e3 = e3 > 0.f ? e3 : 0.2f * e3;
        e4 = e4 > 0.f ? e4 : 0.2f * e4;
        e1 += i > 0   ? 0.f : -1e30f;
        e2 += i < 127 ? 0.f : -1e30f;
        e3 += j > 0   ? 0.f : -1e30f;
        e4 += j < 127 ? 0.f : -1e30f;
        float m = fmaxf(fmaxf(fmaxf(e0, e1), fmaxf(e2, e3)), e4);
        e0 = __expf(e0 - m); e1 = __expf(e1 - m); e2 = __expf(e2 - m);
        e3 = __expf(e3 - m); e4 = __expf(e4 - m);
        float sc = 0.25f / (e0 + e1 + e2 + e3 + e4);   // fold head-mean
        a0 = e0 * sc; a1 = e1 * sc; a2 = e2 * sc; a3 = e3 * sc; a4 = e4 * sc;
    }

    // ---- stencil in reduced space + fold through SGPR w_lin ----
    float gpart[32];
#pragma unroll
    for (int c = 0; c < 32; ++c) gpart[c] = 0.f;

    const float* rp = red_g + (size_t)b * 32 * NN;
    const float* wl_h = w_lin + (size_t)h * 32 * 32;   // SGPR base
#pragma unroll 1
    for (int kc = 0; kc < 4; ++kc) {
        float racc8[8];
#pragma unroll
        for (int i8 = 0; i8 < 8; ++i8) {
            const float* rk = rp + (size_t)(kc * 8 + i8) * NN;
            racc8[i8] = a0 * rk[un0] + a1 * rk[un1] + a2 * rk[un2] +
                        a3 * rk[un3] + a4 * rk[un4];      // coalesced b32 x5
        }
        const float* wk = wl_h + kc * 8;
#pragma unroll
        for (int c = 0; c < 32; ++c) {
            // compile-time offsets from SGPR base -> s_load, SGPR FMA operand
            gpart[c] += wk[c * 32 + 0] * racc8[0] + wk[c * 32 + 1] * racc8[1] +
                        wk[c * 32 + 2] * racc8[2] + wk[c * 32 + 3] * racc8[3] +
                        wk[c * 32 + 4] * racc8[4] + wk[c * 32 + 5] * racc8[5] +
                        wk[c * 32 + 6] * racc8[6] + wk[c * 32 + 7] * racc8[7];
        }
    }

    // ---- head-reduce in c-quarters, fully unrolled (static gpart idx) ----
#pragma unroll
    for (int q = 0; q < 4; ++q) {
#pragma unroll
        for (int cq = 0; cq < 8; ++cq) gp[h][cq][nd] = gpart[q * 8 + cq];
        __syncthreads();
#pragma unroll
        for (int t2 = 0; t2 < 2; ++t2) {
            int cq = h * 2 + t2;
            gout[q * 8 + cq][nd] = gp[0][cq][nd] + gp[1][cq][nd] +
                                   gp[2][cq][nd] + gp[3][cq][nd];
        }
        __syncthreads();
    }

    // ---- restore conv + residual + BN partials: wave owns 16 out-ch ----
    {
        float gv[32];
#pragma unroll
        for (int c = 0; c < 32; ++c) gv[c] = gout[c][nd];
        const float* xb = x + (size_t)b * CINC * NN + v0 + nd;
        float* ob = outp + (size_t)b * CINC * NN + v0 + nd;
        const float* wr_h = w_restore + (size_t)h * 16 * 32;  // SGPR base
#pragma unroll 2
        for (int o16 = 0; o16 < 16; ++o16) {
            int o = h * 16 + o16;
            const float* wr = wr_h + o16 * 32;
            float acc = rb[o];                        // uniform -> s_load
#pragma unroll
            for (int c = 0; c < 32; ++c)
                acc = fmaf(wr[c], gv[c], acc);
            acc += xb[(size_t)o * NN];               // residual
            ob[(size_t)o * NN] = acc;
            float r1 = acc, r2 = acc * acc;
#pragma unroll
            for (int off = 32; off > 0; off >>= 1) {
                r1 += __shfl_xor(r1, off, 64);
                r2 += __shfl_xor(r2, off, 64);
            }
            if (nd == 0) { stat_lds[o] = r1; stat_lds[64 + o] = r2; }
        }
    }
    __syncthreads();
    if (tid < 128) part[(size_t)s * 128 + tid] = stat_lds[tid];  // coalesced
}

// ---------------------------------------------------------------------------
// k2b: reduce per-block partials (2048 x 128, L2-resident) -> stats[128]
// ---------------------------------------------------------------------------
__global__ __launch_bounds__(256) void gat_k2b(
        const float* __restrict__ part, float* __restrict__ stats) {
    __shared__ float red[4];
    int jj = blockIdx.x;       // 0..127: stat index
    int tid = threadIdx.x;
    float acc = 0.f;
    for (int s = tid; s < 2048; s += 256) acc += part[(size_t)s * 128 + jj];
#pragma unroll
    for (int off = 32; off > 0; off >>= 1) acc += __shfl_xor(acc, off, 64);
    int wv = tid >> 6, lane = tid & 63;
    if (lane == 0) red[wv] = acc;
    __syncthreads();
    if (tid == 0) stats[jj] = red[0] + red[1] + red[2] + red[3];
}

// ---------------------------------------------------------------------------
// k3: BN (batch stats) + ReLU, in place on d_out. float4 per thread.
// ---------------------------------------------------------------------------
__global__ __launch_bounds__(256) void gat_k3(
        float* __restrict__ out, const float* __restrict__ stats,
        const float* __restrict__ gamma, const float* __restrict__ beta) {
    int f = blockIdx.x * 256 + threadIdx.x;
    int e = f * 4;
    int c = (e >> 14) & 63;
    const float cnt_inv = 1.f / 131072.f;   // B*H*W
    float mean = stats[c] * cnt_inv;
    float var = stats[64 + c] * cnt_inv - mean * mean;
    float inv = rsqrtf(var + 1e-5f);
    float sc = gamma[c] * inv;
    float sh = beta[c] - mean * sc;
    float4 vv = reinterpret_cast<float4*>(out)[f];
    vv.x = fmaxf(vv.x * sc + sh, 0.f);
    vv.y = fmaxf(vv.y * sc + sh, 0.f);
    vv.z = fmaxf(vv.z * sc + sh, 0.f);
    vv.w = fmaxf(vv.w * sc + sh, 0.f);
    reinterpret_cast<float4*>(out)[f] = vv;
}

// ---------------------------------------------------------------------------
extern "C" void kernel_launch(void* const* d_in, const int* in_sizes, int n_in,
                              void* d_out, int out_size, void* d_ws, size_t ws_size,
                              hipStream_t stream) {
    const float* x         = (const float*)d_in[0];
    const float* w_reduce  = (const float*)d_in[1];
    const float* w_lin     = (const float*)d_in[2];
    const float* att_src   = (const float*)d_in[3];
    const float* att_dst   = (const float*)d_in[4];
    const float* b_gat     = (const float*)d_in[5];
    const float* w_restore = (const float*)d_in[6];
    const float* bn_gamma  = (const float*)d_in[7];
    const float* bn_beta   = (const float*)d_in[8];
    // src/dst (d_in[9], d_in[10]) unused: the grid structure is known.

    float* ws     = (float*)d_ws;
    float* red_g  = ws;                       // 8*32*16384 = 4,194,304
    float* as_ws  = red_g + 4194304;          // 524,288
    float* ad_ws  = as_ws + 524288;           // 524,288
    float* Sf     = ad_ws + 524288;           // 128
    float* Df     = Sf + 128;                 // 128
    float* rbf    = Df + 128;                 // 64
    float* wredT  = rbf + 64;                 // 2048
    float* stats  = wredT + 2048;             // 128
    float* part   = stats + 128;              // 2048*128 = 262,144

    gat_k0<<<1, 256, 0, stream>>>(w_restore, b_gat, w_reduce, w_lin,
                                  att_src, att_dst, rbf, wredT, Sf, Df);
    gat_k1<<<2048, 256, 0, stream>>>(x, wredT, Sf, Df, red_g, as_ws, ad_ws);
    gat_k2<<<2048, 256, 0, stream>>>(x, w_lin, w_restore, rbf, red_g,
                                     as_ws, ad_ws, (float*)d_out, part);
    gat_k2b<<<128, 256, 0, stream>>>(part, stats);
    gat_k3<<<8192, 256, 0, stream>>>((float*)d_out, stats, bn_gamma, bn_beta);
}